// Round 8
// baseline (17535.471 us; speedup 1.0000x reference)
//
#include <hip/hip_runtime.h>
#include <math.h>

#define B_   64
#define T_   256
#define D_   512
#define H_   1024
#define G3_  3072
#define O_   64
#define NTOK (B_*T_)     // 16384
#define TC_  64          // timesteps per chunk
#define NCH_ 4           // chunks

// ---------------------------------------------------------------------------
// init: zero h slot 0 (fp64) and flags. grid 256 x 256.
// ---------------------------------------------------------------------------
__global__ __launch_bounds__(256) void init_ws(double* __restrict__ hs,
                                               int* __restrict__ flags)
{
  int idx = blockIdx.x*256 + threadIdx.x;   // 0..65535
  hs[idx] = 0.0;                            // slot 0 = [64][1024] doubles
  if (idx < 8192) flags[idx] = 0;           // 512 WG flags x 16-int stride
}

// ---------------------------------------------------------------------------
// Stage A (per chunk): gx[(tl*64+b)][g] = emb[x[b,t_base+tl]] . W_ih[g] + b_ih
// R3-proven 64x64 tile structure; fp32 LDS tiles (exact), fp64 FMA accum.
// Block = 64 timesteps of one batch x 64 gates. grid = 64*48 = 3072.
// ---------------------------------------------------------------------------
__global__ __launch_bounds__(256) void stage_a(
    const int* __restrict__ x, const float* __restrict__ emb,
    const float* __restrict__ W_ih, const float* __restrict__ b_ih,
    double* __restrict__ gx, int t_base)
{
  __shared__ float As[64][33];
  __shared__ float Bs[64][33];
  const int tid = threadIdx.x;
  const int b = blockIdx.x & 63, nBlk = blockIdx.x >> 6;
  const int g0 = nBlk*64;

  const int r = tid >> 2, c8 = tid & 3;     // r = t_local row / gate row
  const float* ap = emb  + (size_t)x[b*T_ + t_base + r]*D_ + c8*8;
  const float* bp = W_ih + (size_t)(g0 + r)*D_ + c8*8;
  const int tx = tid & 15, ty = tid >> 4;

  double acc[4][4];
  #pragma unroll
  for (int i = 0; i < 4; ++i)
    #pragma unroll
    for (int j = 0; j < 4; ++j) acc[i][j] = 0.0;

  float4 a0 = *(const float4*)(ap), a1 = *(const float4*)(ap + 4);
  float4 b0 = *(const float4*)(bp), b1 = *(const float4*)(bp + 4);

  for (int kb = 0; kb < 16; ++kb){
    __syncthreads();
    As[r][c8*8+0]=a0.x; As[r][c8*8+1]=a0.y; As[r][c8*8+2]=a0.z; As[r][c8*8+3]=a0.w;
    As[r][c8*8+4]=a1.x; As[r][c8*8+5]=a1.y; As[r][c8*8+6]=a1.z; As[r][c8*8+7]=a1.w;
    Bs[r][c8*8+0]=b0.x; Bs[r][c8*8+1]=b0.y; Bs[r][c8*8+2]=b0.z; Bs[r][c8*8+3]=b0.w;
    Bs[r][c8*8+4]=b1.x; Bs[r][c8*8+5]=b1.y; Bs[r][c8*8+6]=b1.z; Bs[r][c8*8+7]=b1.w;
    __syncthreads();
    if (kb < 15){
      a0 = *(const float4*)(ap + (kb+1)*32);  a1 = *(const float4*)(ap + (kb+1)*32 + 4);
      b0 = *(const float4*)(bp + (kb+1)*32);  b1 = *(const float4*)(bp + (kb+1)*32 + 4);
    }
    #pragma unroll
    for (int k = 0; k < 32; ++k){
      double av[4], bv[4];
      #pragma unroll
      for (int i = 0; i < 4; ++i) av[i] = (double)As[ty*4+i][k];
      #pragma unroll
      for (int j = 0; j < 4; ++j) bv[j] = (double)Bs[tx*4+j][k];
      #pragma unroll
      for (int i = 0; i < 4; ++i)
        #pragma unroll
        for (int j = 0; j < 4; ++j) acc[i][j] = fma(av[i], bv[j], acc[i][j]);
    }
  }

  double bi[4];
  #pragma unroll
  for (int j = 0; j < 4; ++j) bi[j] = (double)b_ih[g0 + tx*4 + j];
  #pragma unroll
  for (int i = 0; i < 4; ++i){
    int tl = ty*4 + i;
    size_t rowoff = ((size_t)tl*B_ + b)*G3_ + g0 + tx*4;
    #pragma unroll
    for (int j = 0; j < 4; ++j)
      gx[rowoff + j] = acc[i][j] + bi[j];
  }
}

// ---------------------------------------------------------------------------
// GRU recurrence (per chunk), fp64 accumulation.
//
// R8: 512 persistent WGs (2/CU -> 8 waves/CU = 2 waves/SIMD), WG wg owns
// h cols wg*2..+1. The R6 inner-loop SCHEDULE is preserved verbatim
// (2 double2 h-streams, float4 W-reads from LDS-fp32, 24 FMA per 4-k iter);
// only the work split changes: per-thread k-range is a QUARTER (256 k),
// reduce gains one shfl_xor(2) level. Rationale: R4/R6/R7 showed the
// 1-wave/SIMD regime's ~33us step floor is phase serialization of a lone
// wave (loads-wait-FMA-wait); a second wave per SIMD overlaps them.
//  - thread = (bq=tid>>3: batch pair, j=(tid>>2)&1: col, quarter=tid&3).
//  - owned cell: b_out = bq*2 + (quarter&1), col jj = wg*2 + j; lanes with
//    quarter>=2 are redundant co-owners (identical values, no store).
//  - LDS W: 6 rows x 4 quarter-slices x 260 floats (260=4 mod 8, 65 quads
//    =1 mod 8): the 8 distinct (j,quarter) wave addresses hit 8 distinct
//    bank-quads -> conflict-free float4 reads. 24.9 KB/WG; 2 WGs fit.
//  - Coherence R1-verbatim: h(t+1) relaxed-agent stores (sc0 sc1 LLC
//    write-through); h(t) plain cached loads (fresh slab); flag store
//    relaxed after vmcnt(0) drain + syncthreads.
//  - Poll: thread tid polls flags of WG tid AND WG tid+256 (512 WGs
//    covered by 256 threads); s_sleep backoff; bounded spin + WG-uniform
//    abort (fail-soft). Flags carry GLOBAL step count.
// ---------------------------------------------------------------------------
__global__ __launch_bounds__(256, 2) void gru_rec(
    const float* __restrict__ W_hh, const float* __restrict__ b_hh,
    const double* __restrict__ gx, double* __restrict__ hs,
    int* __restrict__ flags, int t_base)
{
  __shared__ float Wf[6*4*260];              // 24,960 B; [row=p*2+j][quarter][260]
  __shared__ int abort_flag;
  const int tid = threadIdx.x, wg = blockIdx.x;
  const int i0 = wg*2;
  if (tid == 0) abort_flag = 0;

  for (int it = tid; it < 6*1024; it += 256){
    int rr = it >> 10, k = it & 1023;        // rr = p*2+j
    int p = rr >> 1, j = rr & 1;
    Wf[(rr*4 + (k >> 8))*260 + (k & 255)] = W_hh[(size_t)(p*H_ + i0 + j)*H_ + k];
  }

  const int bq = tid >> 3, j = (tid >> 2) & 1, quarter = tid & 3;
  const int b_out = bq*2 + (quarter & 1);
  const bool owner = (quarter < 2);
  const int jj = i0 + j;
  const double bh0 = (double)b_hh[jj];
  const double bh1 = (double)b_hh[H_   + jj];
  const double bh2 = (double)b_hh[2*H_ + jj];
  const float4* w0p = (const float4*)&Wf[((0*2 + j)*4 + quarter)*260];
  const float4* w1p = (const float4*)&Wf[((1*2 + j)*4 + quarter)*260];
  const float4* w2p = (const float4*)&Wf[((2*2 + j)*4 + quarter)*260];
  __syncthreads();

  // h_prev for this thread's (b_out, jj) cell (redundant lanes track the
  // same value); slot 0 seeded by init_ws or previous gru_rec launch.
  double hprev = hs[(size_t)b_out*H_ + jj];

  for (int tt = 0; tt < TC_; ++tt){
    const int t = t_base + tt;

    // gx is pre-kernel data (stage_a): load BEFORE the spin, hide under it.
    const double* gp = gx + ((size_t)tt*B_ + b_out)*G3_ + jj;
    double gxr = gp[0];
    double gxz = gp[H_];
    double gxn = gp[2*H_];

    {                                        // poll 2 flags (512 WGs / 256 thr)
      int* fp1 = flags + tid*16;
      int* fp2 = flags + (tid + 256)*16;
      int gcnt = 0;
      while (__hip_atomic_load(fp1, __ATOMIC_RELAXED, __HIP_MEMORY_SCOPE_AGENT) < t ||
             __hip_atomic_load(fp2, __ATOMIC_RELAXED, __HIP_MEMORY_SCOPE_AGENT) < t){
        __builtin_amdgcn_s_sleep(2);
        if (++gcnt > (1<<18)) { abort_flag = 1; break; }   // fail-soft
      }
    }
    __syncthreads();                         // releases WG; blocks h-load hoist
    if (abort_flag) break;                   // WG-uniform: all threads bail

    const double2* h0 = (const double2*)(hs + ((size_t)tt*B_ + bq*2    )*H_ + quarter*256);
    const double2* h1 = (const double2*)(hs + ((size_t)tt*B_ + bq*2 + 1)*H_ + quarter*256);

    double pr00=0.0, pr10=0.0, pr20=0.0, pr01=0.0, pr11=0.0, pr21=0.0;
    // 64 iters x 4 k each over this thread's k-quarter; R6 body verbatim.
    #pragma unroll 8
    for (int kk = 0; kk < 64; ++kk){
      double2 a00 = h0[2*kk], a01 = h0[2*kk+1];
      double2 a10 = h1[2*kk], a11 = h1[2*kk+1];
      float4 w0 = w0p[kk];
      float4 w1 = w1p[kk];
      float4 w2 = w2p[kk];
      double w0x=(double)w0.x, w0y=(double)w0.y, w0z=(double)w0.z, w0w=(double)w0.w;
      double w1x=(double)w1.x, w1y=(double)w1.y, w1z=(double)w1.z, w1w=(double)w1.w;
      double w2x=(double)w2.x, w2y=(double)w2.y, w2z=(double)w2.z, w2w=(double)w2.w;
      pr00 = fma(a00.x, w0x, pr00); pr00 = fma(a00.y, w0y, pr00);
      pr00 = fma(a01.x, w0z, pr00); pr00 = fma(a01.y, w0w, pr00);
      pr10 = fma(a00.x, w1x, pr10); pr10 = fma(a00.y, w1y, pr10);
      pr10 = fma(a01.x, w1z, pr10); pr10 = fma(a01.y, w1w, pr10);
      pr20 = fma(a00.x, w2x, pr20); pr20 = fma(a00.y, w2y, pr20);
      pr20 = fma(a01.x, w2z, pr20); pr20 = fma(a01.y, w2w, pr20);
      pr01 = fma(a10.x, w0x, pr01); pr01 = fma(a10.y, w0y, pr01);
      pr01 = fma(a11.x, w0z, pr01); pr01 = fma(a11.y, w0w, pr01);
      pr11 = fma(a10.x, w1x, pr11); pr11 = fma(a10.y, w1y, pr11);
      pr11 = fma(a11.x, w1z, pr11); pr11 = fma(a11.y, w1w, pr11);
      pr21 = fma(a10.x, w2x, pr21); pr21 = fma(a10.y, w2y, pr21);
      pr21 = fma(a11.x, w2z, pr21); pr21 = fma(a11.y, w2w, pr21);
    }
    // reduce over quarters: lane bits 0-1 = quarter (xor 1 then xor 2)
    double s00 = pr00 + __shfl_xor(pr00, 1); s00 += __shfl_xor(s00, 2);
    double s01 = pr01 + __shfl_xor(pr01, 1); s01 += __shfl_xor(s01, 2);
    double s10 = pr10 + __shfl_xor(pr10, 1); s10 += __shfl_xor(s10, 2);
    double s11 = pr11 + __shfl_xor(pr11, 1); s11 += __shfl_xor(s11, 2);
    double s20 = pr20 + __shfl_xor(pr20, 1); s20 += __shfl_xor(s20, 2);
    double s21 = pr21 + __shfl_xor(pr21, 1); s21 += __shfl_xor(s21, 2);
    double ar = (quarter & 1) ? s01 : s00;
    double az = (quarter & 1) ? s11 : s10;
    double an = (quarter & 1) ? s21 : s20;

    double rr_ = 1.0/(1.0 + exp(-(gxr + ar + bh0)));
    double zz  = 1.0/(1.0 + exp(-(gxz + az + bh1)));
    double nn  = tanh(gxn + rr_*(an + bh2));
    double hnew = (1.0 - zz)*nn + zz*hprev;
    hprev = hnew;

    if (owner){
      // LLC-direct (sc0 sc1) stores: agent-visible without release fence.
      __hip_atomic_store(&hs[((size_t)(tt+1)*B_ + b_out)*H_ + jj], hnew,
                         __ATOMIC_RELAXED, __HIP_MEMORY_SCOPE_AGENT);
      if (tt == TC_-1)
        __hip_atomic_store(&hs[(size_t)b_out*H_ + jj], hnew,
                           __ATOMIC_RELAXED, __HIP_MEMORY_SCOPE_AGENT);
    }

    asm volatile("s_waitcnt vmcnt(0)" ::: "memory");  // stores acked at LLC
    __syncthreads();                                  // all 4 waves drained
    if (tid == 0)
      __hip_atomic_store(flags + wg*16, t+1, __ATOMIC_RELAXED, __HIP_MEMORY_SCOPE_AGENT);
  }
}

// ---------------------------------------------------------------------------
// FC + sigmoid + labels (per chunk). fp64 accumulation.
// Labels emulate an fp32 sigmoid+threshold: pf = 1/(1+exp32(-logit32)),
// label = pf > 0.5f. (exp32 emulated as correctly-rounded via fp64 exp.)
// Block = batch b: 64 timesteps x 64 outputs, K=1024. grid 64.
// ---------------------------------------------------------------------------
__global__ __launch_bounds__(256) void fc_out(
    const double* __restrict__ hs, const float* __restrict__ W_fc,
    const float* __restrict__ b_fc, float* __restrict__ out, int t_base)
{
  __shared__ double Ah[64][34];
  __shared__ double Bw[64][34];
  const int tid = threadIdx.x;
  const int b = blockIdx.x;
  const int r = tid >> 2, c8 = tid & 3;
  const double* ap = hs   + ((size_t)(r+1)*B_ + b)*H_ + c8*8;   // slot = tl+1
  const float*  bp = W_fc + (size_t)r*H_ + c8*8;
  const int tx = tid & 15, ty = tid >> 4;

  double acc[4][4];
  #pragma unroll
  for (int i = 0; i < 4; ++i)
    #pragma unroll
    for (int j = 0; j < 4; ++j) acc[i][j] = 0.0;

  double ar0[8]; float br0[8];
  #pragma unroll
  for (int e = 0; e < 8; ++e){ ar0[e] = ap[e]; br0[e] = bp[e]; }

  for (int kb = 0; kb < 32; ++kb){
    __syncthreads();
    #pragma unroll
    for (int e = 0; e < 8; ++e){
      Ah[r][c8*8+e] = ar0[e];
      Bw[r][c8*8+e] = (double)br0[e];
    }
    __syncthreads();
    if (kb < 31){
      #pragma unroll
      for (int e = 0; e < 8; ++e){
        ar0[e] = ap[(kb+1)*32 + e];
        br0[e] = bp[(kb+1)*32 + e];
      }
    }
    #pragma unroll
    for (int k = 0; k < 32; ++k){
      double av[4], bv[4];
      #pragma unroll
      for (int i = 0; i < 4; ++i) av[i] = Ah[ty*4+i][k];
      #pragma unroll
      for (int j = 0; j < 4; ++j) bv[j] = Bw[tx*4+j][k];
      #pragma unroll
      for (int i = 0; i < 4; ++i)
        #pragma unroll
        for (int j = 0; j < 4; ++j) acc[i][j] = fma(av[i], bv[j], acc[i][j]);
    }
  }

  double bi[4];
  #pragma unroll
  for (int j = 0; j < 4; ++j) bi[j] = (double)b_fc[tx*4 + j];
  #pragma unroll
  for (int i = 0; i < 4; ++i){
    int tl = ty*4 + i;
    size_t tok = (size_t)b*T_ + t_base + tl;
    float4 pr, lb;
    float* prp = (float*)&pr; float* lbp = (float*)&lb;
    #pragma unroll
    for (int j = 0; j < 4; ++j){
      double logit = acc[i][j] + bi[j];
      prp[j] = (float)(1.0/(1.0 + exp(-logit)));
      // fp32-sigmoid-emulated label rule:
      float lf = (float)logit;                    // fp32 logit
      float ef = (float)exp(-(double)lf);         // correctly-rounded fp32 exp
      float pf = 1.0f / (1.0f + ef);              // fp32 ops thereafter
      lbp[j] = (pf > 0.5f) ? 1.0f : 0.0f;
    }
    *(float4*)&out[tok*O_ + tx*4] = pr;
    *(float4*)&out[(size_t)NTOK*O_ + tok*O_ + tx*4] = lb;
  }
}

// ---------------------------------------------------------------------------
extern "C" void kernel_launch(void* const* d_in, const int* in_sizes, int n_in,
                              void* d_out, int out_size, void* d_ws, size_t ws_size,
                              hipStream_t stream) {
  const int*   x    = (const int*)  d_in[0];
  const float* emb  = (const float*)d_in[1];
  const float* W_ih = (const float*)d_in[2];
  const float* W_hh = (const float*)d_in[3];
  const float* b_ih = (const float*)d_in[4];
  const float* b_hh = (const float*)d_in[5];
  const float* W_fc = (const float*)d_in[6];
  const float* b_fc = (const float*)d_in[7];
  float* out = (float*)d_out;
  char* ws = (char*)d_ws;

  // ws layout (bytes) — total 134,774,784
  double* gx    = (double*)(ws);                 // 64*64*3072*8  = 100,663,296
  double* hs    = (double*)(ws + 100663296);     // 65*64*1024*8  =  34,078,720
  int*    flags = (int*)   (ws + 134742016);     // 512 WGs x 16 ints = 32,768

  hipLaunchKernelGGL(init_ws, dim3(256), dim3(256), 0, stream, hs, flags);
  for (int c = 0; c < NCH_; ++c){
    int t_base = c*TC_;
    hipLaunchKernelGGL(stage_a, dim3(3072), dim3(256), 0, stream,
                       x, emb, W_ih, b_ih, gx, t_base);
    hipLaunchKernelGGL(gru_rec, dim3(512), dim3(256), 0, stream,
                       W_hh, b_hh, gx, hs, flags, t_base);
    hipLaunchKernelGGL(fc_out, dim3(64), dim3(256), 0, stream,
                       hs, W_fc, b_fc, out, t_base);
  }
}

// Round 9
// 16983.034 us; speedup vs baseline: 1.0325x; 1.0325x over previous
//
#include <hip/hip_runtime.h>
#include <math.h>

#define B_   64
#define T_   256
#define D_   512
#define H_   1024
#define G3_  3072
#define O_   64
#define NTOK (B_*T_)     // 16384
#define TC_  64          // timesteps per chunk
#define NCH_ 4           // chunks

// ---------------------------------------------------------------------------
// init: zero h slot 0 (fp64) and flags. grid 256 x 256.
// ---------------------------------------------------------------------------
__global__ __launch_bounds__(256) void init_ws(double* __restrict__ hs,
                                               int* __restrict__ flags)
{
  int idx = blockIdx.x*256 + threadIdx.x;   // 0..65535
  hs[idx] = 0.0;                            // slot 0 = [64][1024] doubles
  if (idx < 4096) flags[idx] = 0;           // 256 WG flags x 16-int stride
}

// ---------------------------------------------------------------------------
// Stage A (per chunk): gx[(tl*64+b)][g] = emb[x[b,t_base+tl]] . W_ih[g] + b_ih
// R3-proven 64x64 tile structure; fp32 LDS tiles (exact), fp64 FMA accum.
// Block = 64 timesteps of one batch x 64 gates. grid = 64*48 = 3072.
// ---------------------------------------------------------------------------
__global__ __launch_bounds__(256) void stage_a(
    const int* __restrict__ x, const float* __restrict__ emb,
    const float* __restrict__ W_ih, const float* __restrict__ b_ih,
    double* __restrict__ gx, int t_base)
{
  __shared__ float As[64][33];
  __shared__ float Bs[64][33];
  const int tid = threadIdx.x;
  const int b = blockIdx.x & 63, nBlk = blockIdx.x >> 6;
  const int g0 = nBlk*64;

  const int r = tid >> 2, c8 = tid & 3;     // r = t_local row / gate row
  const float* ap = emb  + (size_t)x[b*T_ + t_base + r]*D_ + c8*8;
  const float* bp = W_ih + (size_t)(g0 + r)*D_ + c8*8;
  const int tx = tid & 15, ty = tid >> 4;

  double acc[4][4];
  #pragma unroll
  for (int i = 0; i < 4; ++i)
    #pragma unroll
    for (int j = 0; j < 4; ++j) acc[i][j] = 0.0;

  float4 a0 = *(const float4*)(ap), a1 = *(const float4*)(ap + 4);
  float4 b0 = *(const float4*)(bp), b1 = *(const float4*)(bp + 4);

  for (int kb = 0; kb < 16; ++kb){
    __syncthreads();
    As[r][c8*8+0]=a0.x; As[r][c8*8+1]=a0.y; As[r][c8*8+2]=a0.z; As[r][c8*8+3]=a0.w;
    As[r][c8*8+4]=a1.x; As[r][c8*8+5]=a1.y; As[r][c8*8+6]=a1.z; As[r][c8*8+7]=a1.w;
    Bs[r][c8*8+0]=b0.x; Bs[r][c8*8+1]=b0.y; Bs[r][c8*8+2]=b0.z; Bs[r][c8*8+3]=b0.w;
    Bs[r][c8*8+4]=b1.x; Bs[r][c8*8+5]=b1.y; Bs[r][c8*8+6]=b1.z; Bs[r][c8*8+7]=b1.w;
    __syncthreads();
    if (kb < 15){
      a0 = *(const float4*)(ap + (kb+1)*32);  a1 = *(const float4*)(ap + (kb+1)*32 + 4);
      b0 = *(const float4*)(bp + (kb+1)*32);  b1 = *(const float4*)(bp + (kb+1)*32 + 4);
    }
    #pragma unroll
    for (int k = 0; k < 32; ++k){
      double av[4], bv[4];
      #pragma unroll
      for (int i = 0; i < 4; ++i) av[i] = (double)As[ty*4+i][k];
      #pragma unroll
      for (int j = 0; j < 4; ++j) bv[j] = (double)Bs[tx*4+j][k];
      #pragma unroll
      for (int i = 0; i < 4; ++i)
        #pragma unroll
        for (int j = 0; j < 4; ++j) acc[i][j] = fma(av[i], bv[j], acc[i][j]);
    }
  }

  double bi[4];
  #pragma unroll
  for (int j = 0; j < 4; ++j) bi[j] = (double)b_ih[g0 + tx*4 + j];
  #pragma unroll
  for (int i = 0; i < 4; ++i){
    int tl = ty*4 + i;
    size_t rowoff = ((size_t)tl*B_ + b)*G3_ + g0 + tx*4;
    #pragma unroll
    for (int j = 0; j < 4; ++j)
      gx[rowoff + j] = acc[i][j] + bi[j];
  }
}

// ---------------------------------------------------------------------------
// GRU recurrence (per chunk), fp64. Persistent: 256 WGs of 512 THREADS
// (1 WG/CU, 8 waves/CU = 2 waves/SIMD). WG wg owns h cols wg*4..+3.
//
// R9 = clean TLP test. R1 numeric core & byte-flows preserved EXACTLY:
//  - same 2 double2 h-streams per thread, unroll 8, fp64 Wl[2][12][514]
//    LDS (R1-proven conflict-free; beat R6's fp32 2125 vs 2240);
//  - same column ownership (4 cols/WG -> no h-write fragmentation; R8's
//    2-col split doubled WRITE_SIZE);
//  - same per-CU slab footprint (single WG reads h slab once);
//  - same 256-flag sync protocol (threads 256..511 wait at barrier).
// ONLY delta: each thread covers HALF the k-range (lane bit1 = kh), so
// 8 waves of half-work replace 4 waves of full-work -> 2 waves/SIMD let
// one wave's FMA phase cover the other's load-wait. Reduce adds one
// shfl_xor(2) (kh fold) before the R1 shfl_xor(1) (half exchange).
// Bank note: kh offset = 128 quads = 0 mod 8 -> 16 wave-addresses on
// 8 bank-quads = 2-way aliasing, free per m136.
//
// Thread map: tid = bq*16 + j*4 + kh*2 + half
//   bq 0..31 (batch pair), j 0..3 (col), kh 0..1 (k-half of the half-row),
//   half 0..1 (which 512-double half + batch parity).
//   owned cell: b_out = bq*2 + half, jj = wg*4 + j; kh=1 lanes compute
//   duplicate values (never store).
// Coherence R1-verbatim: h(t+1) relaxed-agent stores (sc0 sc1 LLC
// write-through); h(t) plain cached loads (fresh slab); flag store relaxed
// after vmcnt(0) drain + syncthreads. Flags carry GLOBAL step count.
// Bounded spin + WG-uniform abort (fail-soft).
// ---------------------------------------------------------------------------
__global__ __launch_bounds__(512, 1) void gru_rec(
    const float* __restrict__ W_hh, const float* __restrict__ b_hh,
    const double* __restrict__ gx, double* __restrict__ hs,
    int* __restrict__ flags, int t_base)
{
  __shared__ double Wl[2*12*514];            // [half][rr][514]; rr: 0-3=r,4-7=z,8-11=n
  __shared__ int abort_flag;
  const int tid = threadIdx.x, wg = blockIdx.x;
  const int i0 = wg*4;
  if (tid == 0) abort_flag = 0;

  for (int it = tid; it < 12*1024; it += 512){
    int rr = it >> 10, k = it & 1023;
    int p = rr >> 2, j = rr & 3;
    int hf = k >> 9, kl = k & 511;
    Wl[(hf*12 + rr)*514 + kl] = (double)W_hh[(size_t)(p*H_ + i0 + j)*H_ + k];
  }

  const int bq = tid >> 4, j = (tid >> 2) & 3, kh = (tid >> 1) & 1, half = tid & 1;
  const int b_out = bq*2 + half;
  const int jj = i0 + j;
  const double bh0 = (double)b_hh[jj];
  const double bh1 = (double)b_hh[H_   + jj];
  const double bh2 = (double)b_hh[2*H_ + jj];
  // this thread's quarter-window: doubles [half*512 + kh*256, +256)
  const double2* w0p = (const double2*)&Wl[(half*12 + 0*4 + j)*514 + kh*256];
  const double2* w1p = (const double2*)&Wl[(half*12 + 1*4 + j)*514 + kh*256];
  const double2* w2p = (const double2*)&Wl[(half*12 + 2*4 + j)*514 + kh*256];
  __syncthreads();

  // h_prev for this thread's (b_out, jj) cell (kh=1 lanes mirror it);
  // slot 0 seeded by init_ws (chunk 0) or previous gru_rec launch.
  double hprev = hs[(size_t)b_out*H_ + jj];

  for (int tt = 0; tt < TC_; ++tt){
    const int t = t_base + tt;

    // gx is pre-kernel data (stage_a): load BEFORE the spin, hide under it.
    const double* gp = gx + ((size_t)tt*B_ + b_out)*G3_ + jj;
    double gxr = gp[0];
    double gxz = gp[H_];
    double gxn = gp[2*H_];

    if (tid < 256){                          // R1-verbatim all-flag poll
      int* fp = flags + tid*16;
      int gcnt = 0;
      while (__hip_atomic_load(fp, __ATOMIC_RELAXED, __HIP_MEMORY_SCOPE_AGENT) < t){
        __builtin_amdgcn_s_sleep(2);
        if (++gcnt > (1<<18)) { abort_flag = 1; break; }   // fail-soft
      }
    }
    __syncthreads();                         // releases WG; blocks h-load hoist
    if (abort_flag) break;                   // WG-uniform: all threads bail

    const double2* h0 = (const double2*)(hs + ((size_t)tt*B_ + bq*2    )*H_ + half*512 + kh*256);
    const double2* h1 = (const double2*)(hs + ((size_t)tt*B_ + bq*2 + 1)*H_ + half*512 + kh*256);

    double pr00=0.0, pr10=0.0, pr20=0.0, pr01=0.0, pr11=0.0, pr21=0.0;
    // R1 body verbatim; trip count halved (128 double2 = this k-quarter).
    #pragma unroll 8
    for (int kk = 0; kk < 128; ++kk){
      double2 a0 = h0[kk];
      double2 a1 = h1[kk];
      double2 w0 = w0p[kk];
      double2 w1 = w1p[kk];
      double2 w2 = w2p[kk];
      pr00 = fma(a0.x, w0.x, pr00); pr00 = fma(a0.y, w0.y, pr00);
      pr10 = fma(a0.x, w1.x, pr10); pr10 = fma(a0.y, w1.y, pr10);
      pr20 = fma(a0.x, w2.x, pr20); pr20 = fma(a0.y, w2.y, pr20);
      pr01 = fma(a1.x, w0.x, pr01); pr01 = fma(a1.y, w0.y, pr01);
      pr11 = fma(a1.x, w1.x, pr11); pr11 = fma(a1.y, w1.y, pr11);
      pr21 = fma(a1.x, w2.x, pr21); pr21 = fma(a1.y, w2.y, pr21);
    }
    // fold kh (lane bit1), then R1's half exchange (lane bit0)
    pr00 += __shfl_xor(pr00, 2);  pr01 += __shfl_xor(pr01, 2);
    pr10 += __shfl_xor(pr10, 2);  pr11 += __shfl_xor(pr11, 2);
    pr20 += __shfl_xor(pr20, 2);  pr21 += __shfl_xor(pr21, 2);
    double s00 = pr00 + __shfl_xor(pr00, 1);
    double s01 = pr01 + __shfl_xor(pr01, 1);
    double s10 = pr10 + __shfl_xor(pr10, 1);
    double s11 = pr11 + __shfl_xor(pr11, 1);
    double s20 = pr20 + __shfl_xor(pr20, 1);
    double s21 = pr21 + __shfl_xor(pr21, 1);
    double ar = half ? s01 : s00;
    double az = half ? s11 : s10;
    double an = half ? s21 : s20;

    double rr_ = 1.0/(1.0 + exp(-(gxr + ar + bh0)));
    double zz  = 1.0/(1.0 + exp(-(gxz + az + bh1)));
    double nn  = tanh(gxn + rr_*(an + bh2));
    double hnew = (1.0 - zz)*nn + zz*hprev;
    hprev = hnew;

    if (kh == 0){
      // LLC-direct (sc0 sc1) stores: agent-visible without release fence.
      __hip_atomic_store(&hs[((size_t)(tt+1)*B_ + b_out)*H_ + jj], hnew,
                         __ATOMIC_RELAXED, __HIP_MEMORY_SCOPE_AGENT);
      if (tt == TC_-1)
        __hip_atomic_store(&hs[(size_t)b_out*H_ + jj], hnew,
                           __ATOMIC_RELAXED, __HIP_MEMORY_SCOPE_AGENT);
    }

    asm volatile("s_waitcnt vmcnt(0)" ::: "memory");  // stores acked at LLC
    __syncthreads();                                  // all 8 waves drained
    if (tid == 0)
      __hip_atomic_store(flags + wg*16, t+1, __ATOMIC_RELAXED, __HIP_MEMORY_SCOPE_AGENT);
  }
}

// ---------------------------------------------------------------------------
// FC + sigmoid + labels (per chunk). fp64 accumulation.
// Labels emulate an fp32 sigmoid+threshold: pf = 1/(1+exp32(-logit32)),
// label = pf > 0.5f. (exp32 emulated as correctly-rounded via fp64 exp.)
// Block = batch b: 64 timesteps x 64 outputs, K=1024. grid 64.
// ---------------------------------------------------------------------------
__global__ __launch_bounds__(256) void fc_out(
    const double* __restrict__ hs, const float* __restrict__ W_fc,
    const float* __restrict__ b_fc, float* __restrict__ out, int t_base)
{
  __shared__ double Ah[64][34];
  __shared__ double Bw[64][34];
  const int tid = threadIdx.x;
  const int b = blockIdx.x;
  const int r = tid >> 2, c8 = tid & 3;
  const double* ap = hs   + ((size_t)(r+1)*B_ + b)*H_ + c8*8;   // slot = tl+1
  const float*  bp = W_fc + (size_t)r*H_ + c8*8;
  const int tx = tid & 15, ty = tid >> 4;

  double acc[4][4];
  #pragma unroll
  for (int i = 0; i < 4; ++i)
    #pragma unroll
    for (int j = 0; j < 4; ++j) acc[i][j] = 0.0;

  double ar0[8]; float br0[8];
  #pragma unroll
  for (int e = 0; e < 8; ++e){ ar0[e] = ap[e]; br0[e] = bp[e]; }

  for (int kb = 0; kb < 32; ++kb){
    __syncthreads();
    #pragma unroll
    for (int e = 0; e < 8; ++e){
      Ah[r][c8*8+e] = ar0[e];
      Bw[r][c8*8+e] = (double)br0[e];
    }
    __syncthreads();
    if (kb < 31){
      #pragma unroll
      for (int e = 0; e < 8; ++e){
        ar0[e] = ap[(kb+1)*32 + e];
        br0[e] = bp[(kb+1)*32 + e];
      }
    }
    #pragma unroll
    for (int k = 0; k < 32; ++k){
      double av[4], bv[4];
      #pragma unroll
      for (int i = 0; i < 4; ++i) av[i] = Ah[ty*4+i][k];
      #pragma unroll
      for (int j = 0; j < 4; ++j) bv[j] = Bw[tx*4+j][k];
      #pragma unroll
      for (int i = 0; i < 4; ++i)
        #pragma unroll
        for (int j = 0; j < 4; ++j) acc[i][j] = fma(av[i], bv[j], acc[i][j]);
    }
  }

  double bi[4];
  #pragma unroll
  for (int j = 0; j < 4; ++j) bi[j] = (double)b_fc[tx*4 + j];
  #pragma unroll
  for (int i = 0; i < 4; ++i){
    int tl = ty*4 + i;
    size_t tok = (size_t)b*T_ + t_base + tl;
    float4 pr, lb;
    float* prp = (float*)&pr; float* lbp = (float*)&lb;
    #pragma unroll
    for (int j = 0; j < 4; ++j){
      double logit = acc[i][j] + bi[j];
      prp[j] = (float)(1.0/(1.0 + exp(-logit)));
      // fp32-sigmoid-emulated label rule:
      float lf = (float)logit;                    // fp32 logit
      float ef = (float)exp(-(double)lf);         // correctly-rounded fp32 exp
      float pf = 1.0f / (1.0f + ef);              // fp32 ops thereafter
      lbp[j] = (pf > 0.5f) ? 1.0f : 0.0f;
    }
    *(float4*)&out[tok*O_ + tx*4] = pr;
    *(float4*)&out[(size_t)NTOK*O_ + tok*O_ + tx*4] = lb;
  }
}

// ---------------------------------------------------------------------------
extern "C" void kernel_launch(void* const* d_in, const int* in_sizes, int n_in,
                              void* d_out, int out_size, void* d_ws, size_t ws_size,
                              hipStream_t stream) {
  const int*   x    = (const int*)  d_in[0];
  const float* emb  = (const float*)d_in[1];
  const float* W_ih = (const float*)d_in[2];
  const float* W_hh = (const float*)d_in[3];
  const float* b_ih = (const float*)d_in[4];
  const float* b_hh = (const float*)d_in[5];
  const float* W_fc = (const float*)d_in[6];
  const float* b_fc = (const float*)d_in[7];
  float* out = (float*)d_out;
  char* ws = (char*)d_ws;

  // ws layout (bytes) — total 134,758,400
  double* gx    = (double*)(ws);                 // 64*64*3072*8  = 100,663,296
  double* hs    = (double*)(ws + 100663296);     // 65*64*1024*8  =  34,078,720
  int*    flags = (int*)   (ws + 134742016);     // 256 WGs x 16 ints

  hipLaunchKernelGGL(init_ws, dim3(256), dim3(256), 0, stream, hs, flags);
  for (int c = 0; c < NCH_; ++c){
    int t_base = c*TC_;
    hipLaunchKernelGGL(stage_a, dim3(3072), dim3(256), 0, stream,
                       x, emb, W_ih, b_ih, gx, t_base);
    hipLaunchKernelGGL(gru_rec, dim3(256), dim3(512), 0, stream,
                       W_hh, b_hh, gx, hs, flags, t_base);
    hipLaunchKernelGGL(fc_out, dim3(64), dim3(256), 0, stream,
                       hs, W_fc, b_fc, out, t_base);
  }
}

// Round 10
// 9881.111 us; speedup vs baseline: 1.7746x; 1.7187x over previous
//
#include <hip/hip_runtime.h>
#include <math.h>

#define B_   64
#define T_   256
#define D_   512
#define H_   1024
#define G3_  3072
#define O_   64
#define NTOK (B_*T_)     // 16384
#define TC_  64          // timesteps per chunk
#define NCH_ 4           // chunks

// ---------------------------------------------------------------------------
// init: zero h slot 0 (fp64) and flags. grid 256 x 256.
// ---------------------------------------------------------------------------
__global__ __launch_bounds__(256) void init_ws(double* __restrict__ hs,
                                               int* __restrict__ flags)
{
  int idx = blockIdx.x*256 + threadIdx.x;   // 0..65535
  hs[idx] = 0.0;                            // slot 0 = [64][1024] doubles
  if (idx < 4096) flags[idx] = 0;
}

// ---------------------------------------------------------------------------
// Stage A (per chunk): gx[(tl*64+b)][g] = emb[x[b,t_base+tl]] . W_ih[g] + b_ih
// R3-proven 64x64 tile structure; fp32 LDS tiles (exact), fp64 FMA accum.
// Block = 64 timesteps of one batch x 64 gates. grid = 64*48 = 3072.
// ---------------------------------------------------------------------------
__global__ __launch_bounds__(256) void stage_a(
    const int* __restrict__ x, const float* __restrict__ emb,
    const float* __restrict__ W_ih, const float* __restrict__ b_ih,
    double* __restrict__ gx, int t_base)
{
  __shared__ float As[64][33];
  __shared__ float Bs[64][33];
  const int tid = threadIdx.x;
  const int b = blockIdx.x & 63, nBlk = blockIdx.x >> 6;
  const int g0 = nBlk*64;

  const int r = tid >> 2, c8 = tid & 3;     // r = t_local row / gate row
  const float* ap = emb  + (size_t)x[b*T_ + t_base + r]*D_ + c8*8;
  const float* bp = W_ih + (size_t)(g0 + r)*D_ + c8*8;
  const int tx = tid & 15, ty = tid >> 4;

  double acc[4][4];
  #pragma unroll
  for (int i = 0; i < 4; ++i)
    #pragma unroll
    for (int j = 0; j < 4; ++j) acc[i][j] = 0.0;

  float4 a0 = *(const float4*)(ap), a1 = *(const float4*)(ap + 4);
  float4 b0 = *(const float4*)(bp), b1 = *(const float4*)(bp + 4);

  for (int kb = 0; kb < 16; ++kb){
    __syncthreads();
    As[r][c8*8+0]=a0.x; As[r][c8*8+1]=a0.y; As[r][c8*8+2]=a0.z; As[r][c8*8+3]=a0.w;
    As[r][c8*8+4]=a1.x; As[r][c8*8+5]=a1.y; As[r][c8*8+6]=a1.z; As[r][c8*8+7]=a1.w;
    Bs[r][c8*8+0]=b0.x; Bs[r][c8*8+1]=b0.y; Bs[r][c8*8+2]=b0.z; Bs[r][c8*8+3]=b0.w;
    Bs[r][c8*8+4]=b1.x; Bs[r][c8*8+5]=b1.y; Bs[r][c8*8+6]=b1.z; Bs[r][c8*8+7]=b1.w;
    __syncthreads();
    if (kb < 15){
      a0 = *(const float4*)(ap + (kb+1)*32);  a1 = *(const float4*)(ap + (kb+1)*32 + 4);
      b0 = *(const float4*)(bp + (kb+1)*32);  b1 = *(const float4*)(bp + (kb+1)*32 + 4);
    }
    #pragma unroll
    for (int k = 0; k < 32; ++k){
      double av[4], bv[4];
      #pragma unroll
      for (int i = 0; i < 4; ++i) av[i] = (double)As[ty*4+i][k];
      #pragma unroll
      for (int j = 0; j < 4; ++j) bv[j] = (double)Bs[tx*4+j][k];
      #pragma unroll
      for (int i = 0; i < 4; ++i)
        #pragma unroll
        for (int j = 0; j < 4; ++j) acc[i][j] = fma(av[i], bv[j], acc[i][j]);
    }
  }

  double bi[4];
  #pragma unroll
  for (int j = 0; j < 4; ++j) bi[j] = (double)b_ih[g0 + tx*4 + j];
  #pragma unroll
  for (int i = 0; i < 4; ++i){
    int tl = ty*4 + i;
    size_t rowoff = ((size_t)tl*B_ + b)*G3_ + g0 + tx*4;
    #pragma unroll
    for (int j = 0; j < 4; ++j)
      gx[rowoff + j] = acc[i][j] + bi[j];
  }
}

// ---------------------------------------------------------------------------
// GRU recurrence (per chunk), fp64. Persistent: 256 WGs (1/CU), WG wg owns
// h cols wg*4..+3; its 12 W_hh gate-rows live in LDS as fp64.
//
// R10 = R1 restored verbatim — the measured optimum of this session.
// Evidence: R1 2125us (best); R4 sync-tree 2185 (neutral); R6 fp32-LDS 2240
// (neutral => LDS BW off critical path); R7 unroll-16 2286 (neutral => ILP
// depth off critical path); R2/R5/R8/R9 restructures 3500-4000 (negative:
// added waves / changed streams / split ownership all regress).
//
// Scheme (validated):
//  - h(t+1) stores: RELAXED agent-scope atomics -> sc0 sc1 write-through to
//    LLC (coherence point), no release fence (no buffer_wbl2).
//  - h(t) loads: NORMAL cached loads. Safe: hs is slabbed [65][B][H]; no
//    slab address is read before written within the kernel, so L1/L2 never
//    hold stale copies. No acquire fence (no buffer_inv).
//  - flag store: relaxed agent atomic, ordered behind h stores by explicit
//    vmcnt(0) drain + __syncthreads.
//  - LDS layout Wl[half][12][514]: bank quad = 16*half + 4*j -> the 8
//    distinct (j,half) addresses of each ds_read_b128 cover all 32 banks
//    exactly once (conflict-free; measured 0 conflicts).
//  - gx loads hoisted before the flag spin (independent of h; latency hides
//    under the spin). h_prev kept in register (thread owns its (b,col) cell).
// Flags carry GLOBAL step count (monotone across chunks). Bounded spin with
// WG-uniform abort (fail-soft).
// ---------------------------------------------------------------------------
__global__ __launch_bounds__(256, 1) void gru_rec(
    const float* __restrict__ W_hh, const float* __restrict__ b_hh,
    const double* __restrict__ gx, double* __restrict__ hs,
    int* __restrict__ flags, int t_base)
{
  __shared__ double Wl[2*12*514];            // [half][rr][514]; rr: 0-3=r,4-7=z,8-11=n
  __shared__ int abort_flag;
  const int tid = threadIdx.x, wg = blockIdx.x;
  const int i0 = wg*4;
  if (tid == 0) abort_flag = 0;

  for (int it = tid; it < 12*1024; it += 256){
    int rr = it >> 10, k = it & 1023;
    int p = rr >> 2, j = rr & 3;
    int hf = k >> 9, kl = k & 511;
    Wl[(hf*12 + rr)*514 + kl] = (double)W_hh[(size_t)(p*H_ + i0 + j)*H_ + k];
  }

  const int bq = tid >> 3, j = (tid >> 1) & 3, half = tid & 1;
  const int b_out = bq*2 + half;
  const int jj = i0 + j;
  const double bh0 = (double)b_hh[jj];
  const double bh1 = (double)b_hh[H_   + jj];
  const double bh2 = (double)b_hh[2*H_ + jj];
  const double2* w0p = (const double2*)&Wl[(half*12 + 0*4 + j)*514];
  const double2* w1p = (const double2*)&Wl[(half*12 + 1*4 + j)*514];
  const double2* w2p = (const double2*)&Wl[(half*12 + 2*4 + j)*514];
  __syncthreads();

  // h_prev for this thread's own (b_out, jj) cell; slot 0 seeded by
  // init_ws (chunk 0) or previous gru_rec launch (kernel-boundary coherent).
  double hprev = hs[(size_t)b_out*H_ + jj];

  for (int tt = 0; tt < TC_; ++tt){
    const int t = t_base + tt;

    // gx is pre-kernel data (stage_a): load BEFORE the spin, hide under it.
    const double* gp = gx + ((size_t)tt*B_ + b_out)*G3_ + jj;
    double gxr = gp[0];
    double gxz = gp[H_];
    double gxn = gp[2*H_];

    {
      int* fp = flags + tid*16;
      int gcnt = 0;
      while (__hip_atomic_load(fp, __ATOMIC_RELAXED, __HIP_MEMORY_SCOPE_AGENT) < t){
        __builtin_amdgcn_s_sleep(2);
        if (++gcnt > (1<<18)) { abort_flag = 1; break; }   // fail-soft
      }
    }
    __syncthreads();                         // also blocks hoist of h loads
    if (abort_flag) break;                   // WG-uniform: all threads bail

    const double2* h0 = (const double2*)(hs + ((size_t)tt*B_ + bq*2    )*H_ + half*512);
    const double2* h1 = (const double2*)(hs + ((size_t)tt*B_ + bq*2 + 1)*H_ + half*512);

    double pr00=0.0, pr10=0.0, pr20=0.0, pr01=0.0, pr11=0.0, pr21=0.0;
    #pragma unroll 8
    for (int kk = 0; kk < 256; ++kk){
      double2 a0 = h0[kk];
      double2 a1 = h1[kk];
      double2 w0 = w0p[kk];
      double2 w1 = w1p[kk];
      double2 w2 = w2p[kk];
      pr00 = fma(a0.x, w0.x, pr00); pr00 = fma(a0.y, w0.y, pr00);
      pr10 = fma(a0.x, w1.x, pr10); pr10 = fma(a0.y, w1.y, pr10);
      pr20 = fma(a0.x, w2.x, pr20); pr20 = fma(a0.y, w2.y, pr20);
      pr01 = fma(a1.x, w0.x, pr01); pr01 = fma(a1.y, w0.y, pr01);
      pr11 = fma(a1.x, w1.x, pr11); pr11 = fma(a1.y, w1.y, pr11);
      pr21 = fma(a1.x, w2.x, pr21); pr21 = fma(a1.y, w2.y, pr21);
    }
    double s00 = pr00 + __shfl_xor(pr00, 1);
    double s01 = pr01 + __shfl_xor(pr01, 1);
    double s10 = pr10 + __shfl_xor(pr10, 1);
    double s11 = pr11 + __shfl_xor(pr11, 1);
    double s20 = pr20 + __shfl_xor(pr20, 1);
    double s21 = pr21 + __shfl_xor(pr21, 1);
    double ar = half ? s01 : s00;
    double az = half ? s11 : s10;
    double an = half ? s21 : s20;

    double rr_ = 1.0/(1.0 + exp(-(gxr + ar + bh0)));
    double zz  = 1.0/(1.0 + exp(-(gxz + az + bh1)));
    double nn  = tanh(gxn + rr_*(an + bh2));
    double hnew = (1.0 - zz)*nn + zz*hprev;
    hprev = hnew;

    // LLC-direct (sc0 sc1) stores: agent-visible without any release fence.
    __hip_atomic_store(&hs[((size_t)(tt+1)*B_ + b_out)*H_ + jj], hnew,
                       __ATOMIC_RELAXED, __HIP_MEMORY_SCOPE_AGENT);
    if (tt == TC_-1)
      __hip_atomic_store(&hs[(size_t)b_out*H_ + jj], hnew,
                         __ATOMIC_RELAXED, __HIP_MEMORY_SCOPE_AGENT);

    asm volatile("s_waitcnt vmcnt(0)" ::: "memory");  // stores acked at LLC
    __syncthreads();                                  // all 4 waves drained
    if (tid == 0)
      __hip_atomic_store(flags + wg*16, t+1, __ATOMIC_RELAXED, __HIP_MEMORY_SCOPE_AGENT);
  }
}

// ---------------------------------------------------------------------------
// FC + sigmoid + labels (per chunk). fp64 accumulation.
// Labels emulate an fp32 sigmoid+threshold: pf = 1/(1+exp32(-logit32)),
// label = pf > 0.5f. (exp32 emulated as correctly-rounded via fp64 exp.)
// Block = batch b: 64 timesteps x 64 outputs, K=1024. grid 64.
// ---------------------------------------------------------------------------
__global__ __launch_bounds__(256) void fc_out(
    const double* __restrict__ hs, const float* __restrict__ W_fc,
    const float* __restrict__ b_fc, float* __restrict__ out, int t_base)
{
  __shared__ double Ah[64][34];
  __shared__ double Bw[64][34];
  const int tid = threadIdx.x;
  const int b = blockIdx.x;
  const int r = tid >> 2, c8 = tid & 3;
  const double* ap = hs   + ((size_t)(r+1)*B_ + b)*H_ + c8*8;   // slot = tl+1
  const float*  bp = W_fc + (size_t)r*H_ + c8*8;
  const int tx = tid & 15, ty = tid >> 4;

  double acc[4][4];
  #pragma unroll
  for (int i = 0; i < 4; ++i)
    #pragma unroll
    for (int j = 0; j < 4; ++j) acc[i][j] = 0.0;

  double ar0[8]; float br0[8];
  #pragma unroll
  for (int e = 0; e < 8; ++e){ ar0[e] = ap[e]; br0[e] = bp[e]; }

  for (int kb = 0; kb < 32; ++kb){
    __syncthreads();
    #pragma unroll
    for (int e = 0; e < 8; ++e){
      Ah[r][c8*8+e] = ar0[e];
      Bw[r][c8*8+e] = (double)br0[e];
    }
    __syncthreads();
    if (kb < 31){
      #pragma unroll
      for (int e = 0; e < 8; ++e){
        ar0[e] = ap[(kb+1)*32 + e];
        br0[e] = bp[(kb+1)*32 + e];
      }
    }
    #pragma unroll
    for (int k = 0; k < 32; ++k){
      double av[4], bv[4];
      #pragma unroll
      for (int i = 0; i < 4; ++i) av[i] = Ah[ty*4+i][k];
      #pragma unroll
      for (int j = 0; j < 4; ++j) bv[j] = Bw[tx*4+j][k];
      #pragma unroll
      for (int i = 0; i < 4; ++i)
        #pragma unroll
        for (int j = 0; j < 4; ++j) acc[i][j] = fma(av[i], bv[j], acc[i][j]);
    }
  }

  double bi[4];
  #pragma unroll
  for (int j = 0; j < 4; ++j) bi[j] = (double)b_fc[tx*4 + j];
  #pragma unroll
  for (int i = 0; i < 4; ++i){
    int tl = ty*4 + i;
    size_t tok = (size_t)b*T_ + t_base + tl;
    float4 pr, lb;
    float* prp = (float*)&pr; float* lbp = (float*)&lb;
    #pragma unroll
    for (int j = 0; j < 4; ++j){
      double logit = acc[i][j] + bi[j];
      prp[j] = (float)(1.0/(1.0 + exp(-logit)));
      // fp32-sigmoid-emulated label rule:
      float lf = (float)logit;                    // fp32 logit
      float ef = (float)exp(-(double)lf);         // correctly-rounded fp32 exp
      float pf = 1.0f / (1.0f + ef);              // fp32 ops thereafter
      lbp[j] = (pf > 0.5f) ? 1.0f : 0.0f;
    }
    *(float4*)&out[tok*O_ + tx*4] = pr;
    *(float4*)&out[(size_t)NTOK*O_ + tok*O_ + tx*4] = lb;
  }
}

// ---------------------------------------------------------------------------
extern "C" void kernel_launch(void* const* d_in, const int* in_sizes, int n_in,
                              void* d_out, int out_size, void* d_ws, size_t ws_size,
                              hipStream_t stream) {
  const int*   x    = (const int*)  d_in[0];
  const float* emb  = (const float*)d_in[1];
  const float* W_ih = (const float*)d_in[2];
  const float* W_hh = (const float*)d_in[3];
  const float* b_ih = (const float*)d_in[4];
  const float* b_hh = (const float*)d_in[5];
  const float* W_fc = (const float*)d_in[6];
  const float* b_fc = (const float*)d_in[7];
  float* out = (float*)d_out;
  char* ws = (char*)d_ws;

  // ws layout (bytes) — total 134,758,400
  double* gx    = (double*)(ws);                 // 64*64*3072*8  = 100,663,296
  double* hs    = (double*)(ws + 100663296);     // 65*64*1024*8  =  34,078,720
  int*    flags = (int*)   (ws + 134742016);     // 16,384

  hipLaunchKernelGGL(init_ws, dim3(256), dim3(256), 0, stream, hs, flags);
  for (int c = 0; c < NCH_; ++c){
    int t_base = c*TC_;
    hipLaunchKernelGGL(stage_a, dim3(3072), dim3(256), 0, stream,
                       x, emb, W_ih, b_ih, gx, t_base);
    hipLaunchKernelGGL(gru_rec, dim3(256), dim3(256), 0, stream,
                       W_hh, b_hh, gx, hs, flags, t_base);
    hipLaunchKernelGGL(fc_out, dim3(64), dim3(256), 0, stream,
                       hs, W_fc, b_fc, out, t_base);
  }
}